// Round 12
// baseline (208.809 us; speedup 1.0000x reference)
//
#include <hip/hip_runtime.h>

// ---------------------------------------------------------------------------
// GraphSAGE 2-layer (mean aggr), N=100000, E=1600000, 128 -> 128(relu) -> 64
// Project-then-aggregate; bf16 MFMA GEMMs; fp8 gathered features both layers
// (xq 12.8 MB, hl 6.4 MB); CSR via LDS-binned counting sort (512-block
// partition); aggregation = wave-per-node, 32 cache lines in flight per wave
// (measured at the ~2.8 TB/s random-line fabric ceiling).
// ---------------------------------------------------------------------------

namespace {
constexpr int NN   = 100000;
constexpr int NE   = 1600000;
constexpr int NBKT = 391;            // buckets of 256 nodes: dst >> 8
constexpr int PB   = 512;            // partition blocks
constexpr int CE   = NE / PB;        // 3125 edges per partition block

// workspace layout in 4-byte words (16B-aligned regions)
constexpr size_t W_BKT  = 0;         // int[392]  bucket counts
constexpr size_t W_BASE = 400;       // int[392]  bucket bases (excl scan)
constexpr size_t W_BCUR = 800;       // int[392]  bucket alloc cursors
constexpr size_t W_OFF  = 1200;      // int[100416] CSR row offsets
constexpr size_t W_PART = 101616;    // int[NE]   bucket-sorted packed edges
constexpr size_t W_CSR  = 1701616;   // int[NE]   CSR adjacency (src ids)
constexpr size_t W_B1   = 3301616;   // ushort[8*8*64*8] packed W1
constexpr size_t W_B2   = 3318000;   // ushort[4*8*64*8] packed W2
constexpr size_t W_XQ   = 3326192;   // fp8  [NN][128]  (xl, gathered, 12.8 MB)
constexpr size_t W_XR   = 6526192;   // bf16 [NN][128]  (xr, self path)
constexpr size_t W_H    = 12926192;  // bf16 [NN][128]
constexpr size_t W_HL   = 19326192;  // fp8  [NN][64]   (hl, gathered, 6.4 MB)
constexpr size_t W_HR   = 20926192;  // bf16 [NN][64]   (hr, self path)
// end = 24,126,192 words = 96.5 MB
}

using short8  = __attribute__((ext_vector_type(8)))  short;
using f32x16  = __attribute__((ext_vector_type(16))) float;
using floatx2 = __attribute__((ext_vector_type(2)))  float;

__device__ inline unsigned short f2b(float f) {   // fp32 -> bf16 RNE
  unsigned u = __builtin_bit_cast(unsigned, f);
  u = (u + 0x7fffu + ((u >> 16) & 1u)) >> 16;
  return (unsigned short)u;
}
__device__ inline float b2f_lo(unsigned u) { return __builtin_bit_cast(float, u << 16); }
__device__ inline float b2f_hi(unsigned u) { return __builtin_bit_cast(float, u & 0xffff0000u); }
__device__ inline float b2f(unsigned short s) { return __builtin_bit_cast(float, ((unsigned)s) << 16); }

// ---------------- CSR build: LDS-binned counting sort ----------------

__global__ __launch_bounds__(256) void prebucket_k(const int* __restrict__ dst,
                                                   int* __restrict__ bktCnt) {
  __shared__ int h[NBKT];
  int t = threadIdx.x;
  for (int j = t; j < NBKT; j += 256) h[j] = 0;
  __syncthreads();
  const int base = blockIdx.x * CE;
  for (int i = t; i < CE; i += 256) atomicAdd(&h[dst[base + i] >> 8], 1);
  __syncthreads();
  for (int j = t; j < NBKT; j += 256) if (h[j]) atomicAdd(&bktCnt[j], h[j]);
}

__global__ __launch_bounds__(512) void scanb_k(const int* __restrict__ bktCnt,
                                               int* __restrict__ bktBase,
                                               int* __restrict__ bktCur) {
  __shared__ int s[512];
  int t = threadIdx.x;
  int v = (t < NBKT) ? bktCnt[t] : 0;
  s[t] = v;
  __syncthreads();
  #pragma unroll
  for (int d = 1; d < 512; d <<= 1) {
    int u = (t >= d) ? s[t - d] : 0;
    __syncthreads();
    s[t] += u;
    __syncthreads();
  }
  int excl = s[t] - v;
  if (t <= NBKT) bktBase[t] = excl;       // bktBase[NBKT] = NE sentinel
  if (t < NBKT)  bktCur[t]  = excl;
}

__global__ __launch_bounds__(256) void partition_k(const int* __restrict__ src,
                                                   const int* __restrict__ dst,
                                                   int* __restrict__ bktCur,
                                                   int* __restrict__ part) {
  __shared__ int  hist[NBKT + 1];
  __shared__ int  lo[NBKT + 1];
  __shared__ int  cur[NBKT + 1];
  __shared__ int  gb[NBKT + 1];
  __shared__ int  sh[256];
  __shared__ int  stage[CE];
  __shared__ unsigned short sbkt[CE];
  int t = threadIdx.x;
  const int base = blockIdx.x * CE;

  for (int j = t; j < NBKT + 1; j += 256) hist[j] = 0;
  __syncthreads();
  for (int i = t; i < CE; i += 256) atomicAdd(&hist[dst[base + i] >> 8], 1);
  __syncthreads();

  int j0 = 2 * t, j1 = 2 * t + 1;
  int h0 = (j0 < NBKT) ? hist[j0] : 0;
  int h1 = (j1 < NBKT) ? hist[j1] : 0;
  int ps = h0 + h1;
  sh[t] = ps;
  __syncthreads();
  #pragma unroll
  for (int d = 1; d < 256; d <<= 1) {
    int u = (t >= d) ? sh[t - d] : 0;
    __syncthreads();
    sh[t] += u;
    __syncthreads();
  }
  int e0 = sh[t] - ps;
  if (j0 < NBKT + 1) { lo[j0] = e0; cur[j0] = e0; }
  if (j1 < NBKT + 1) { lo[j1] = e0 + h0; cur[j1] = e0 + h0; }
  __syncthreads();

  for (int i = t; i < CE; i += 256) {
    int d = dst[base + i], s = src[base + i];
    int b = d >> 8;
    int p = atomicAdd(&cur[b], 1);
    stage[p] = ((d & 255) << 23) | s;
    sbkt[p]  = (unsigned short)b;
  }
  __syncthreads();

  for (int j = t; j < NBKT; j += 256)
    gb[j] = hist[j] ? atomicAdd(&bktCur[j], hist[j]) : 0;
  __syncthreads();

  for (int i = t; i < CE; i += 256) {
    int b = sbkt[i];
    part[gb[b] + (i - lo[b])] = stage[i];
  }
}

__global__ __launch_bounds__(512) void cfill_k(const int* __restrict__ part,
                                               const int* __restrict__ bktBase,
                                               int* __restrict__ off,
                                               int* __restrict__ csr) {
  __shared__ int cnt[256];
  __shared__ int cur[256];
  __shared__ int sh[256];
  int t = threadIdx.x;
  const int b = blockIdx.x;
  const int beg = bktBase[b], end = bktBase[b + 1];

  if (t < 256) cnt[t] = 0;
  __syncthreads();
  for (int i = beg + t; i < end; i += 512)
    atomicAdd(&cnt[((unsigned)part[i]) >> 23], 1);
  __syncthreads();

  int v = (t < 256) ? cnt[t] : 0;
  if (t < 256) sh[t] = v;
  __syncthreads();
  #pragma unroll
  for (int d = 1; d < 256; d <<= 1) {
    int u = (t >= d && t < 256) ? sh[t - d] : 0;
    __syncthreads();
    if (t < 256) sh[t] += u;
    __syncthreads();
  }
  if (t < 256) {
    int excl = sh[t] - v;
    off[b * 256 + t] = beg + excl;
    cur[t] = excl;
  }
  __syncthreads();

  for (int i = beg + t; i < end; i += 512) {
    int w = part[i];
    int j = ((unsigned)w) >> 23;
    int p = atomicAdd(&cur[j], 1);
    csr[beg + p] = w & 0x7FFFFF;
  }
}

// ---------------- pack weights into 32x32x16 MFMA B-fragment order ---------

__global__ void prep_b_k(const float* __restrict__ w1l, const float* __restrict__ w1r,
                         const float* __restrict__ w2l, const float* __restrict__ w2r,
                         unsigned short* __restrict__ b1p, unsigned short* __restrict__ b2p) {
  int e = blockIdx.x * blockDim.x + threadIdx.x;
  if (e >= 6144) return;
  bool g2 = e >= 4096;
  int le = g2 ? e - 4096 : e;
  int nf = le >> 9, kk = (le >> 6) & 7, l = le & 63;
  int n = nf * 32 + (l & 31), half = l >> 5;
  const float* Wlo = g2 ? w2l : w1l;
  const float* Whi = g2 ? w2r : w1r;
  int split = g2 ? 64 : 128;
  unsigned short o[8];
  #pragma unroll
  for (int j = 0; j < 8; ++j) {
    int k = kk * 16 + ((j >= 4) ? 8 : 0) + half * 4 + (j & 3);
    float v = (n < split) ? Wlo[(size_t)n * 128 + k] : Whi[(size_t)(n - split) * 128 + k];
    o[j] = f2b(v);
  }
  unsigned short* dstp = (g2 ? b2p : b1p) + (size_t)le * 8;
  *(short8*)dstp = __builtin_bit_cast(short8, *(const ulonglong2*)o);
}

// ---------------- MFMA GEMM: C[m,n] = sum_k A[m,k]*W[n,k], K=128 ----------
// MODE 1: cols <128 -> fp8 e4m3 to C2 ([M][128]); cols >=128 -> bf16 to C ([M][128]).
// MODE 2: cols <64  -> fp8 e4m3 to C ([M][64]);   cols >=64  -> bf16 to C2 ([M][64]).

template<int NCOLS, bool AFP32, int MODE>
__global__ __launch_bounds__(512, 2) void gemm_k(const void* __restrict__ Aptr, int M,
                                                 const unsigned short* __restrict__ Bpack,
                                                 void* __restrict__ Cv,
                                                 void* __restrict__ C2v) {
  constexpr int NF = NCOLS / 64;          // n-frags per wave
  __shared__ unsigned short As[128 * 128];
  const int t  = threadIdx.x;
  const int m0 = blockIdx.x * 128;

  #pragma unroll
  for (int i = 0; i < 4; ++i) {
    int G = t + 512 * i;
    int r = G >> 4, g = G & 15;
    int m = m0 + r;
    short8 v = {0, 0, 0, 0, 0, 0, 0, 0};
    if (AFP32) {
      if (m < M) {
        const float* p = (const float*)Aptr + (size_t)m * 128 + g * 8;
        float4 a = *(const float4*)p;
        float4 b = *(const float4*)(p + 4);
        v[0] = (short)f2b(a.x); v[1] = (short)f2b(a.y);
        v[2] = (short)f2b(a.z); v[3] = (short)f2b(a.w);
        v[4] = (short)f2b(b.x); v[5] = (short)f2b(b.y);
        v[6] = (short)f2b(b.z); v[7] = (short)f2b(b.w);
      }
    } else {
      if (m < M) v = *(const short8*)((const unsigned short*)Aptr + (size_t)m * 128 + g * 8);
    }
    *(short8*)(As + r * 128 + ((g ^ (r & 15)) << 3)) = v;
  }
  __syncthreads();

  const int wid = t >> 6, lane = t & 63;
  const int mw = wid >> 1, nw = wid & 1;
  const int m = mw * 32 + (lane & 31), half = lane >> 5;

  short8 af[8];
  #pragma unroll
  for (int kk = 0; kk < 8; ++kk) {
    const unsigned* p0 = (const unsigned*)(As + m * 128 + (((2 * kk)     ^ (m & 15)) << 3) + half * 4);
    const unsigned* p1 = (const unsigned*)(As + m * 128 + (((2 * kk + 1) ^ (m & 15)) << 3) + half * 4);
    uint4 comb = make_uint4(p0[0], p0[1], p1[0], p1[1]);
    af[kk] = __builtin_bit_cast(short8, comb);
  }

  #pragma unroll
  for (int nf = 0; nf < NF; ++nf) {
    const int nfg = nw * NF + nf;
    f32x16 acc;
    #pragma unroll
    for (int i = 0; i < 16; ++i) acc[i] = 0.f;
    #pragma unroll
    for (int kk = 0; kk < 8; ++kk) {
      short8 bf = *(const short8*)(Bpack + ((size_t)((nfg * 8 + kk) * 64 + lane)) * 8);
      acc = __builtin_amdgcn_mfma_f32_32x32x16_bf16(af[kk], bf, acc, 0, 0, 0);
    }
    const int col = nfg * 32 + (lane & 31);
    #pragma unroll
    for (int q = 0; q < 4; ++q)
      #pragma unroll
      for (int rr = 0; rr < 4; ++rr) {
        int row = rr + 8 * q + 4 * half;
        int mo  = m0 + mw * 32 + row;
        if (mo < M) {
          float v = acc[q * 4 + rr];
          if (MODE == 1) {
            if (col < 128) {
              int p8 = __builtin_amdgcn_cvt_pk_fp8_f32(v, v, 0, false);
              ((unsigned char*)C2v)[(size_t)mo * 128 + col] = (unsigned char)(p8 & 0xff);
            } else {
              ((unsigned short*)Cv)[(size_t)mo * 128 + (col - 128)] = f2b(v);
            }
          } else {  // MODE 2
            if (col < 64) {
              int p8 = __builtin_amdgcn_cvt_pk_fp8_f32(v, v, 0, false);
              ((unsigned char*)Cv)[(size_t)mo * 64 + col] = (unsigned char)(p8 & 0xff);
            } else {
              ((unsigned short*)C2v)[(size_t)mo * 64 + (col - 64)] = f2b(v);
            }
          }
        }
      }
  }
}

// ---------------- layer-1 aggregate + bias + self + relu -------------------
// wave per node; 4 groups of 16 lanes; each group gathers 4 different edges'
// full fp8 rows (uint2 = 8 B/lane x 16 lanes = 128 B) -> 16 edges / 32 lines
// in flight per wave (measured at ~2.8 TB/s L2-miss fabric ceiling).

__global__ __launch_bounds__(256) void agg1_k(const unsigned char* __restrict__ xq,
                                              const unsigned short* __restrict__ xr,
                                              const int* __restrict__ off,
                                              const int* __restrict__ csr,
                                              const float* __restrict__ b1,
                                              unsigned short* __restrict__ h) {
  int wid  = (blockIdx.x * blockDim.x + threadIdx.x) >> 6;
  int lane = threadIdx.x & 63;
  if (wid >= NN) return;
  const int g = lane >> 4, sub = lane & 15;
  int s0 = off[wid], s1 = off[wid + 1];

  float acc[8];
  #pragma unroll
  for (int k = 0; k < 8; ++k) acc[k] = 0.f;

  for (int e = s0; e < s1; e += 16) {
    int e0 = e + g, e1 = e + 4 + g, e2 = e + 8 + g, e3 = e + 12 + g;
    uint2 v0 = make_uint2(0u, 0u), v1 = make_uint2(0u, 0u);
    uint2 v2 = make_uint2(0u, 0u), v3 = make_uint2(0u, 0u);
    if (e0 < s1) v0 = *(const uint2*)(xq + (size_t)csr[e0] * 128 + sub * 8);
    if (e1 < s1) v1 = *(const uint2*)(xq + (size_t)csr[e1] * 128 + sub * 8);
    if (e2 < s1) v2 = *(const uint2*)(xq + (size_t)csr[e2] * 128 + sub * 8);
    if (e3 < s1) v3 = *(const uint2*)(xq + (size_t)csr[e3] * 128 + sub * 8);
    floatx2 f;
    f = __builtin_amdgcn_cvt_pk_f32_fp8(v0.x, false); acc[0] += f.x; acc[1] += f.y;
    f = __builtin_amdgcn_cvt_pk_f32_fp8(v0.x, true);  acc[2] += f.x; acc[3] += f.y;
    f = __builtin_amdgcn_cvt_pk_f32_fp8(v0.y, false); acc[4] += f.x; acc[5] += f.y;
    f = __builtin_amdgcn_cvt_pk_f32_fp8(v0.y, true);  acc[6] += f.x; acc[7] += f.y;
    f = __builtin_amdgcn_cvt_pk_f32_fp8(v1.x, false); acc[0] += f.x; acc[1] += f.y;
    f = __builtin_amdgcn_cvt_pk_f32_fp8(v1.x, true);  acc[2] += f.x; acc[3] += f.y;
    f = __builtin_amdgcn_cvt_pk_f32_fp8(v1.y, false); acc[4] += f.x; acc[5] += f.y;
    f = __builtin_amdgcn_cvt_pk_f32_fp8(v1.y, true);  acc[6] += f.x; acc[7] += f.y;
    f = __builtin_amdgcn_cvt_pk_f32_fp8(v2.x, false); acc[0] += f.x; acc[1] += f.y;
    f = __builtin_amdgcn_cvt_pk_f32_fp8(v2.x, true);  acc[2] += f.x; acc[3] += f.y;
    f = __builtin_amdgcn_cvt_pk_f32_fp8(v2.y, false); acc[4] += f.x; acc[5] += f.y;
    f = __builtin_amdgcn_cvt_pk_f32_fp8(v2.y, true);  acc[6] += f.x; acc[7] += f.y;
    f = __builtin_amdgcn_cvt_pk_f32_fp8(v3.x, false); acc[0] += f.x; acc[1] += f.y;
    f = __builtin_amdgcn_cvt_pk_f32_fp8(v3.x, true);  acc[2] += f.x; acc[3] += f.y;
    f = __builtin_amdgcn_cvt_pk_f32_fp8(v3.y, false); acc[4] += f.x; acc[5] += f.y;
    f = __builtin_amdgcn_cvt_pk_f32_fp8(v3.y, true);  acc[6] += f.x; acc[7] += f.y;
  }

  #pragma unroll
  for (int k = 0; k < 8; ++k) {
    acc[k] += __shfl_xor(acc[k], 16);
    acc[k] += __shfl_xor(acc[k], 32);
  }

  float inv = 1.f / fmaxf((float)(s1 - s0), 1.f);
  int widx = sub * 4 + g;                  // uint word -> cols 2*widx, 2*widx+1
  unsigned su = ((const unsigned*)xr)[(size_t)wid * 64 + widx];
  float2 bb = *(const float2*)(b1 + 2 * widx);
  float h0 = fmaxf(fmaf(acc[2 * g],     inv, bb.x + b2f_lo(su)), 0.f);
  float h1 = fmaxf(fmaf(acc[2 * g + 1], inv, bb.y + b2f_hi(su)), 0.f);
  unsigned packed = (unsigned)f2b(h0) | ((unsigned)f2b(h1) << 16);
  ((unsigned*)h)[(size_t)wid * 64 + widx] = packed;
}

// ---------------- layer-2 aggregate + bias + self -> out (fp32) ------------
// grouped-gather; hl row = 64 fp8 = 64 B (one uint/lane); 8 gathers per
// group -> 32 edges / 32 lines in flight per wave.

__global__ __launch_bounds__(256) void agg2_k(const unsigned char* __restrict__ hl,
                                              const unsigned short* __restrict__ hr,
                                              const int* __restrict__ off,
                                              const int* __restrict__ csr,
                                              const float* __restrict__ b2,
                                              float* __restrict__ out) {
  int wid  = (blockIdx.x * blockDim.x + threadIdx.x) >> 6;
  int lane = threadIdx.x & 63;
  if (wid >= NN) return;
  const int g = lane >> 4, sub = lane & 15;
  int s0 = off[wid], s1 = off[wid + 1];

  float acc[4];
  #pragma unroll
  for (int k = 0; k < 4; ++k) acc[k] = 0.f;

  for (int e = s0; e < s1; e += 32) {
    unsigned v[8];
    #pragma unroll
    for (int k = 0; k < 8; ++k) {
      int ee = e + 4 * k + g;
      v[k] = 0u;
      if (ee < s1) v[k] = *(const unsigned*)(hl + (size_t)csr[ee] * 64 + sub * 4);
    }
    #pragma unroll
    for (int k = 0; k < 8; ++k) {
      floatx2 f;
      f = __builtin_amdgcn_cvt_pk_f32_fp8(v[k], false); acc[0] += f.x; acc[1] += f.y;
      f = __builtin_amdgcn_cvt_pk_f32_fp8(v[k], true);  acc[2] += f.x; acc[3] += f.y;
    }
  }

  #pragma unroll
  for (int k = 0; k < 4; ++k) {
    acc[k] += __shfl_xor(acc[k], 16);
    acc[k] += __shfl_xor(acc[k], 32);
  }

  float inv = 1.f / fmaxf((float)(s1 - s0), 1.f);
  int c = sub * 4 + g;                     // output column this lane writes
  float r = b2f(hr[(size_t)wid * 64 + c]);
  out[(size_t)wid * 64 + c] = fmaf(acc[g], inv, b2[c] + r);
}

// ---------------- launch ----------------

extern "C" void kernel_launch(void* const* d_in, const int* in_sizes, int n_in,
                              void* d_out, int out_size, void* d_ws, size_t ws_size,
                              hipStream_t stream) {
  const float* x   = (const float*)d_in[0];
  const int*   ei  = (const int*)d_in[1];
  const float* w1l = (const float*)d_in[2];
  const float* b1  = (const float*)d_in[3];
  const float* w1r = (const float*)d_in[4];
  const float* w2l = (const float*)d_in[5];
  const float* b2  = (const float*)d_in[6];
  const float* w2r = (const float*)d_in[7];
  float* out = (float*)d_out;

  const int* src = ei;
  const int* dst = ei + NE;

  int* bktCnt  = (int*)d_ws + W_BKT;
  int* bktBase = (int*)d_ws + W_BASE;
  int* bktCur  = (int*)d_ws + W_BCUR;
  int* off     = (int*)d_ws + W_OFF;
  int* part    = (int*)d_ws + W_PART;
  int* csr     = (int*)d_ws + W_CSR;
  unsigned short* b1p = (unsigned short*)((int*)d_ws + W_B1);
  unsigned short* b2p = (unsigned short*)((int*)d_ws + W_B2);
  unsigned char*  xq  = (unsigned char*)((int*)d_ws + W_XQ);   // fp8 [NN][128]
  unsigned short* xr  = (unsigned short*)((int*)d_ws + W_XR);  // bf16 [NN][128]
  unsigned short* h   = (unsigned short*)((int*)d_ws + W_H);   // bf16 [NN][128]
  unsigned char*  hl  = (unsigned char*)((int*)d_ws + W_HL);   // fp8 [NN][64]
  unsigned short* hr  = (unsigned short*)((int*)d_ws + W_HR);  // bf16 [NN][64]

  hipMemsetAsync(bktCnt, 0, 400 * 4, stream);

  prebucket_k<<<PB, 256, 0, stream>>>(dst, bktCnt);
  scanb_k<<<1, 512, 0, stream>>>(bktCnt, bktBase, bktCur);
  partition_k<<<PB, 256, 0, stream>>>(src, dst, bktCur, part);
  cfill_k<<<NBKT, 512, 0, stream>>>(part, bktBase, off, csr);
  prep_b_k<<<24, 256, 0, stream>>>(w1l, w1r, w2l, w2r, b1p, b2p);

  const int gb = (NN + 127) / 128;   // 782
  const int ab = (NN * 64 + 255) / 256;

  // GEMM1: xq = fp8(x @ W1l^T) [NN][128], xr = bf16(x @ W1r^T) [NN][128]
  gemm_k<256, true, 1><<<gb, 512, 0, stream>>>((const void*)x, NN, b1p, xr, xq);

  // agg1: h = bf16( relu(mean_fp8(xl) + b1 + xr) )
  agg1_k<<<ab, 256, 0, stream>>>(xq, xr, off, csr, b1, h);

  // GEMM2: hl = fp8(h @ W2l^T) [NN][64], hr = bf16(h @ W2r^T) [NN][64]
  gemm_k<128, false, 2><<<gb, 512, 0, stream>>>((const void*)h, NN, b2p, hl, hr);

  // agg2: out = mean_fp8(hl) + b2 + hr  (fp32)
  agg2_k<<<ab, 256, 0, stream>>>(hl, hr, off, csr, b2, out);
}

// Round 13
// 205.390 us; speedup vs baseline: 1.0166x; 1.0166x over previous
//
#include <hip/hip_runtime.h>

// ---------------------------------------------------------------------------
// GraphSAGE 2-layer (mean aggr), N=100000, E=1600000, 128 -> 128(relu) -> 64
// Project-then-aggregate; bf16 MFMA GEMMs with LDS-repacked coalesced
// epilogues; fp8 gathered features both layers (xq 12.8 MB, hl 6.4 MB);
// CSR via LDS-binned counting sort; aggregation = wave-per-node, 32 cache
// lines in flight per wave (at the ~2.8 TB/s random-line fabric ceiling).
// ---------------------------------------------------------------------------

namespace {
constexpr int NN   = 100000;
constexpr int NE   = 1600000;
constexpr int NBKT = 391;            // buckets of 256 nodes: dst >> 8
constexpr int PB   = 256;            // partition blocks
constexpr int CE   = NE / PB;        // 6250 edges per partition block

// workspace layout in 4-byte words (16B-aligned regions)
constexpr size_t W_BKT  = 0;         // int[392]  bucket counts
constexpr size_t W_BASE = 400;       // int[392]  bucket bases (excl scan)
constexpr size_t W_BCUR = 800;       // int[392]  bucket alloc cursors
constexpr size_t W_OFF  = 1200;      // int[100416] CSR row offsets
constexpr size_t W_PART = 101616;    // int[NE]   bucket-sorted packed edges
constexpr size_t W_CSR  = 1701616;   // int[NE]   CSR adjacency (src ids)
constexpr size_t W_B1   = 3301616;   // ushort[8*8*64*8] packed W1
constexpr size_t W_B2   = 3318000;   // ushort[4*8*64*8] packed W2
constexpr size_t W_XQ   = 3326192;   // fp8  [NN][128]  (xl, gathered, 12.8 MB)
constexpr size_t W_XR   = 6526192;   // bf16 [NN][128]  (xr, self path)
constexpr size_t W_H    = 12926192;  // bf16 [NN][128]
constexpr size_t W_HL   = 19326192;  // fp8  [NN][64]   (hl, gathered, 6.4 MB)
constexpr size_t W_HR   = 20926192;  // bf16 [NN][64]   (hr, self path)
// end = 24,126,192 words = 96.5 MB
}

using short8  = __attribute__((ext_vector_type(8)))  short;
using f32x16  = __attribute__((ext_vector_type(16))) float;
using floatx2 = __attribute__((ext_vector_type(2)))  float;

__device__ inline unsigned short f2b(float f) {   // fp32 -> bf16 RNE
  unsigned u = __builtin_bit_cast(unsigned, f);
  u = (u + 0x7fffu + ((u >> 16) & 1u)) >> 16;
  return (unsigned short)u;
}
__device__ inline float b2f_lo(unsigned u) { return __builtin_bit_cast(float, u << 16); }
__device__ inline float b2f_hi(unsigned u) { return __builtin_bit_cast(float, u & 0xffff0000u); }
__device__ inline float b2f(unsigned short s) { return __builtin_bit_cast(float, ((unsigned)s) << 16); }

// ---------------- CSR build: LDS-binned counting sort ----------------

__global__ __launch_bounds__(256) void prebucket_k(const int* __restrict__ dst,
                                                   int* __restrict__ bktCnt) {
  __shared__ int h[NBKT];
  int t = threadIdx.x;
  for (int j = t; j < NBKT; j += 256) h[j] = 0;
  __syncthreads();
  const int base = blockIdx.x * CE;
  for (int i = t; i < CE; i += 256) atomicAdd(&h[dst[base + i] >> 8], 1);
  __syncthreads();
  for (int j = t; j < NBKT; j += 256) if (h[j]) atomicAdd(&bktCnt[j], h[j]);
}

__global__ __launch_bounds__(512) void scanb_k(const int* __restrict__ bktCnt,
                                               int* __restrict__ bktBase,
                                               int* __restrict__ bktCur) {
  __shared__ int s[512];
  int t = threadIdx.x;
  int v = (t < NBKT) ? bktCnt[t] : 0;
  s[t] = v;
  __syncthreads();
  #pragma unroll
  for (int d = 1; d < 512; d <<= 1) {
    int u = (t >= d) ? s[t - d] : 0;
    __syncthreads();
    s[t] += u;
    __syncthreads();
  }
  int excl = s[t] - v;
  if (t <= NBKT) bktBase[t] = excl;       // bktBase[NBKT] = NE sentinel
  if (t < NBKT)  bktCur[t]  = excl;
}

__global__ __launch_bounds__(256) void partition_k(const int* __restrict__ src,
                                                   const int* __restrict__ dst,
                                                   int* __restrict__ bktCur,
                                                   int* __restrict__ part) {
  __shared__ int  hist[NBKT + 1];
  __shared__ int  lo[NBKT + 1];
  __shared__ int  cur[NBKT + 1];
  __shared__ int  gb[NBKT + 1];
  __shared__ int  sh[256];
  __shared__ int  stage[CE];
  __shared__ unsigned short sbkt[CE];
  int t = threadIdx.x;
  const int base = blockIdx.x * CE;

  for (int j = t; j < NBKT + 1; j += 256) hist[j] = 0;
  __syncthreads();
  for (int i = t; i < CE; i += 256) atomicAdd(&hist[dst[base + i] >> 8], 1);
  __syncthreads();

  int j0 = 2 * t, j1 = 2 * t + 1;
  int h0 = (j0 < NBKT) ? hist[j0] : 0;
  int h1 = (j1 < NBKT) ? hist[j1] : 0;
  int ps = h0 + h1;
  sh[t] = ps;
  __syncthreads();
  #pragma unroll
  for (int d = 1; d < 256; d <<= 1) {
    int u = (t >= d) ? sh[t - d] : 0;
    __syncthreads();
    sh[t] += u;
    __syncthreads();
  }
  int e0 = sh[t] - ps;
  if (j0 < NBKT + 1) { lo[j0] = e0; cur[j0] = e0; }
  if (j1 < NBKT + 1) { lo[j1] = e0 + h0; cur[j1] = e0 + h0; }
  __syncthreads();

  for (int i = t; i < CE; i += 256) {
    int d = dst[base + i], s = src[base + i];
    int b = d >> 8;
    int p = atomicAdd(&cur[b], 1);
    stage[p] = ((d & 255) << 23) | s;
    sbkt[p]  = (unsigned short)b;
  }
  __syncthreads();

  for (int j = t; j < NBKT; j += 256)
    gb[j] = hist[j] ? atomicAdd(&bktCur[j], hist[j]) : 0;
  __syncthreads();

  for (int i = t; i < CE; i += 256) {
    int b = sbkt[i];
    part[gb[b] + (i - lo[b])] = stage[i];
  }
}

__global__ __launch_bounds__(256) void cfill_k(const int* __restrict__ part,
                                               const int* __restrict__ bktBase,
                                               int* __restrict__ off,
                                               int* __restrict__ csr) {
  __shared__ int cnt[256];
  __shared__ int cur[256];
  __shared__ int sh[256];
  int t = threadIdx.x;
  const int b = blockIdx.x;
  const int beg = bktBase[b], end = bktBase[b + 1];

  cnt[t] = 0;
  __syncthreads();
  for (int i = beg + t; i < end; i += 256)
    atomicAdd(&cnt[((unsigned)part[i]) >> 23], 1);
  __syncthreads();

  int v = cnt[t];
  sh[t] = v;
  __syncthreads();
  #pragma unroll
  for (int d = 1; d < 256; d <<= 1) {
    int u = (t >= d) ? sh[t - d] : 0;
    __syncthreads();
    sh[t] += u;
    __syncthreads();
  }
  int excl = sh[t] - v;
  off[b * 256 + t] = beg + excl;
  cur[t] = excl;
  __syncthreads();

  for (int i = beg + t; i < end; i += 256) {
    int w = part[i];
    int j = ((unsigned)w) >> 23;
    int p = atomicAdd(&cur[j], 1);
    csr[beg + p] = w & 0x7FFFFF;
  }
}

// ---------------- pack weights into 32x32x16 MFMA B-fragment order ---------

__global__ void prep_b_k(const float* __restrict__ w1l, const float* __restrict__ w1r,
                         const float* __restrict__ w2l, const float* __restrict__ w2r,
                         unsigned short* __restrict__ b1p, unsigned short* __restrict__ b2p) {
  int e = blockIdx.x * blockDim.x + threadIdx.x;
  if (e >= 6144) return;
  bool g2 = e >= 4096;
  int le = g2 ? e - 4096 : e;
  int nf = le >> 9, kk = (le >> 6) & 7, l = le & 63;
  int n = nf * 32 + (l & 31), half = l >> 5;
  const float* Wlo = g2 ? w2l : w1l;
  const float* Whi = g2 ? w2r : w1r;
  int split = g2 ? 64 : 128;
  unsigned short o[8];
  #pragma unroll
  for (int j = 0; j < 8; ++j) {
    int k = kk * 16 + ((j >= 4) ? 8 : 0) + half * 4 + (j & 3);
    float v = (n < split) ? Wlo[(size_t)n * 128 + k] : Whi[(size_t)(n - split) * 128 + k];
    o[j] = f2b(v);
  }
  unsigned short* dstp = (g2 ? b2p : b1p) + (size_t)le * 8;
  *(short8*)dstp = __builtin_bit_cast(short8, *(const ulonglong2*)o);
}

// ---------------- MFMA GEMM: C[m,n] = sum_k A[m,k]*W[n,k], K=128 ----------
// LDS-repacked epilogue: acc -> LDS tile image (fp8 + bf16 regions), then
// coalesced uint4 stores.
// MODE 1: cols <128 -> fp8 to C2v ([M][128]); cols >=128 -> bf16 to Cv ([M][128]).
// MODE 2: cols <64  -> fp8 to Cv  ([M][64]);  cols >=64  -> bf16 to C2v ([M][64]).

template<int NCOLS, bool AFP32, int MODE>
__global__ __launch_bounds__(512, 2) void gemm_k(const void* __restrict__ Aptr, int M,
                                                 const unsigned short* __restrict__ Bpack,
                                                 void* __restrict__ Cv,
                                                 void* __restrict__ C2v) {
  constexpr int NF = NCOLS / 64;                 // n-frags per wave
  constexpr int QB = (MODE == 1) ? 128 : 64;     // fp8 cols per row
  constexpr int EPI = 128 * QB * 3;              // fp8 bytes + bf16 bytes
  constexpr int SZ  = EPI > 32768 ? EPI : 32768; // >= staging (32 KB)
  __shared__ __align__(16) char smem[SZ];
  unsigned short* As    = (unsigned short*)smem;
  unsigned char*  epi_q = (unsigned char*)smem;            // [128][QB] fp8
  unsigned short* epi_r = (unsigned short*)(smem + 128 * QB); // [128][QB] bf16

  const int t  = threadIdx.x;
  const int m0 = blockIdx.x * 128;

  // ---- stage A (bf16, XOR-swizzled 16B granules) ----
  #pragma unroll
  for (int i = 0; i < 4; ++i) {
    int G = t + 512 * i;
    int r = G >> 4, g = G & 15;
    int m = m0 + r;
    short8 v = {0, 0, 0, 0, 0, 0, 0, 0};
    if (AFP32) {
      if (m < M) {
        const float* p = (const float*)Aptr + (size_t)m * 128 + g * 8;
        float4 a = *(const float4*)p;
        float4 b = *(const float4*)(p + 4);
        v[0] = (short)f2b(a.x); v[1] = (short)f2b(a.y);
        v[2] = (short)f2b(a.z); v[3] = (short)f2b(a.w);
        v[4] = (short)f2b(b.x); v[5] = (short)f2b(b.y);
        v[6] = (short)f2b(b.z); v[7] = (short)f2b(b.w);
      }
    } else {
      if (m < M) v = *(const short8*)((const unsigned short*)Aptr + (size_t)m * 128 + g * 8);
    }
    *(short8*)(As + r * 128 + ((g ^ (r & 15)) << 3)) = v;
  }
  __syncthreads();

  const int wid = t >> 6, lane = t & 63;
  const int mw = wid >> 1, nw = wid & 1;
  const int m = mw * 32 + (lane & 31), half = lane >> 5;

  // ---- A fragments into registers (all K) ----
  short8 af[8];
  #pragma unroll
  for (int kk = 0; kk < 8; ++kk) {
    const unsigned* p0 = (const unsigned*)(As + m * 128 + (((2 * kk)     ^ (m & 15)) << 3) + half * 4);
    const unsigned* p1 = (const unsigned*)(As + m * 128 + (((2 * kk + 1) ^ (m & 15)) << 3) + half * 4);
    uint4 comb = make_uint4(p0[0], p0[1], p1[0], p1[1]);
    af[kk] = __builtin_bit_cast(short8, comb);
  }
  __syncthreads();   // all As reads done -> smem reusable as epilogue buffer

  // ---- MFMA + scatter into LDS epilogue image ----
  #pragma unroll
  for (int nf = 0; nf < NF; ++nf) {
    const int nfg = nw * NF + nf;
    f32x16 acc;
    #pragma unroll
    for (int i = 0; i < 16; ++i) acc[i] = 0.f;
    #pragma unroll
    for (int kk = 0; kk < 8; ++kk) {
      short8 bf = *(const short8*)(Bpack + ((size_t)((nfg * 8 + kk) * 64 + lane)) * 8);
      acc = __builtin_amdgcn_mfma_f32_32x32x16_bf16(af[kk], bf, acc, 0, 0, 0);
    }
    const int col = nfg * 32 + (lane & 31);
    #pragma unroll
    for (int q = 0; q < 4; ++q)
      #pragma unroll
      for (int rr = 0; rr < 4; ++rr) {
        int lr = mw * 32 + rr + 8 * q + 4 * half;     // local row 0..127
        float v = acc[q * 4 + rr];
        if (col < QB) {
          int p8 = __builtin_amdgcn_cvt_pk_fp8_f32(v, v, 0, false);
          epi_q[lr * QB + col] = (unsigned char)(p8 & 0xff);
        } else {
          epi_r[lr * QB + (col - QB)] = f2b(v);
        }
      }
  }
  __syncthreads();

  // ---- coalesced store-out ----
  if (MODE == 1) {
    // xq fp8: 128 x 128 B = 16 KB (1024 x 16 B)
    #pragma unroll
    for (int i = 0; i < 2; ++i) {
      int idx = t + 512 * i;
      int row = idx >> 3, c16 = idx & 7;
      int mo = m0 + row;
      if (mo < M)
        *(uint4*)((unsigned char*)C2v + (size_t)mo * 128 + c16 * 16) =
            *(const uint4*)(epi_q + row * 128 + c16 * 16);
    }
    // xr bf16: 128 x 256 B = 32 KB (2048 x 16 B)
    #pragma unroll
    for (int i = 0; i < 4; ++i) {
      int idx = t + 512 * i;
      int row = idx >> 4, c16 = idx & 15;
      int mo = m0 + row;
      if (mo < M)
        *(uint4*)((unsigned char*)Cv + (size_t)mo * 256 + c16 * 16) =
            *(const uint4*)((const unsigned char*)epi_r + row * 256 + c16 * 16);
    }
  } else {
    // hl fp8: 128 x 64 B = 8 KB (512 x 16 B)
    {
      int row = t >> 2, c16 = t & 3;
      int mo = m0 + row;
      if (mo < M)
        *(uint4*)((unsigned char*)Cv + (size_t)mo * 64 + c16 * 16) =
            *(const uint4*)(epi_q + row * 64 + c16 * 16);
    }
    // hr bf16: 128 x 128 B = 16 KB (1024 x 16 B)
    #pragma unroll
    for (int i = 0; i < 2; ++i) {
      int idx = t + 512 * i;
      int row = idx >> 3, c16 = idx & 7;
      int mo = m0 + row;
      if (mo < M)
        *(uint4*)((unsigned char*)C2v + (size_t)mo * 128 + c16 * 16) =
            *(const uint4*)((const unsigned char*)epi_r + row * 128 + c16 * 16);
    }
  }
}

// ---------------- layer-1 aggregate + bias + self + relu -------------------
// wave per node; 4 groups of 16 lanes; each group gathers 4 different edges'
// full fp8 rows (uint2 = 8 B/lane x 16 lanes = 128 B) -> 16 edges / 32 lines
// in flight per wave (measured at ~2.8 TB/s L2-miss fabric ceiling).

__global__ __launch_bounds__(256) void agg1_k(const unsigned char* __restrict__ xq,
                                              const unsigned short* __restrict__ xr,
                                              const int* __restrict__ off,
                                              const int* __restrict__ csr,
                                              const float* __restrict__ b1,
                                              unsigned short* __restrict__ h) {
  int wid  = (blockIdx.x * blockDim.x + threadIdx.x) >> 6;
  int lane = threadIdx.x & 63;
  if (wid >= NN) return;
  const int g = lane >> 4, sub = lane & 15;
  int s0 = off[wid], s1 = off[wid + 1];

  float acc[8];
  #pragma unroll
  for (int k = 0; k < 8; ++k) acc[k] = 0.f;

  for (int e = s0; e < s1; e += 16) {
    int e0 = e + g, e1 = e + 4 + g, e2 = e + 8 + g, e3 = e + 12 + g;
    uint2 v0 = make_uint2(0u, 0u), v1 = make_uint2(0u, 0u);
    uint2 v2 = make_uint2(0u, 0u), v3 = make_uint2(0u, 0u);
    if (e0 < s1) v0 = *(const uint2*)(xq + (size_t)csr[e0] * 128 + sub * 8);
    if (e1 < s1) v1 = *(const uint2*)(xq + (size_t)csr[e1] * 128 + sub * 8);
    if (e2 < s1) v2 = *(const uint2*)(xq + (size_t)csr[e2] * 128 + sub * 8);
    if (e3 < s1) v3 = *(const uint2*)(xq + (size_t)csr[e3] * 128 + sub * 8);
    floatx2 f;
    f = __builtin_amdgcn_cvt_pk_f32_fp8(v0.x, false); acc[0] += f.x; acc[1] += f.y;
    f = __builtin_amdgcn_cvt_pk_f32_fp8(v0.x, true);  acc[2] += f.x; acc[3] += f.y;
    f = __builtin_amdgcn_cvt_pk_f32_fp8(v0.y, false); acc[4] += f.x; acc[5] += f.y;
    f = __builtin_amdgcn_cvt_pk_f32_fp8(v0.y, true);  acc[6] += f.x; acc[7] += f.y;
    f = __builtin_amdgcn_cvt_pk_f32_fp8(v1.x, false); acc[0] += f.x; acc[1] += f.y;
    f = __builtin_amdgcn_cvt_pk_f32_fp8(v1.x, true);  acc[2] += f.x; acc[3] += f.y;
    f = __builtin_amdgcn_cvt_pk_f32_fp8(v1.y, false); acc[4] += f.x; acc[5] += f.y;
    f = __builtin_amdgcn_cvt_pk_f32_fp8(v1.y, true);  acc[6] += f.x; acc[7] += f.y;
    f = __builtin_amdgcn_cvt_pk_f32_fp8(v2.x, false); acc[0] += f.x; acc[1] += f.y;
    f = __builtin_amdgcn_cvt_pk_f32_fp8(v2.x, true);  acc[2] += f.x; acc[3] += f.y;
    f = __builtin_amdgcn_cvt_pk_f32_fp8(v2.y, false); acc[4] += f.x; acc[5] += f.y;
    f = __builtin_amdgcn_cvt_pk_f32_fp8(v2.y, true);  acc[6] += f.x; acc[7] += f.y;
    f = __builtin_amdgcn_cvt_pk_f32_fp8(v3.x, false); acc[0] += f.x; acc[1] += f.y;
    f = __builtin_amdgcn_cvt_pk_f32_fp8(v3.x, true);  acc[2] += f.x; acc[3] += f.y;
    f = __builtin_amdgcn_cvt_pk_f32_fp8(v3.y, false); acc[4] += f.x; acc[5] += f.y;
    f = __builtin_amdgcn_cvt_pk_f32_fp8(v3.y, true);  acc[6] += f.x; acc[7] += f.y;
  }

  #pragma unroll
  for (int k = 0; k < 8; ++k) {
    acc[k] += __shfl_xor(acc[k], 16);
    acc[k] += __shfl_xor(acc[k], 32);
  }

  float inv = 1.f / fmaxf((float)(s1 - s0), 1.f);
  int widx = sub * 4 + g;                  // uint word -> cols 2*widx, 2*widx+1
  unsigned su = ((const unsigned*)xr)[(size_t)wid * 64 + widx];
  float2 bb = *(const float2*)(b1 + 2 * widx);
  float h0 = fmaxf(fmaf(acc[2 * g],     inv, bb.x + b2f_lo(su)), 0.f);
  float h1 = fmaxf(fmaf(acc[2 * g + 1], inv, bb.y + b2f_hi(su)), 0.f);
  unsigned packed = (unsigned)f2b(h0) | ((unsigned)f2b(h1) << 16);
  ((unsigned*)h)[(size_t)wid * 64 + widx] = packed;
}

// ---------------- layer-2 aggregate + bias + self -> out (fp32) ------------
// grouped-gather; hl row = 64 fp8 = 64 B (one uint/lane); 8 gathers per
// group -> 32 edges / 32 lines in flight per wave.

__global__ __launch_bounds__(256) void agg2_k(const unsigned char* __restrict__ hl,
                                              const unsigned short* __restrict__ hr,
                                              const int* __restrict__ off,
                                              const int* __restrict__ csr,
                                              const float* __restrict__ b2,
                                              float* __restrict__ out) {
  int wid  = (blockIdx.x * blockDim.x + threadIdx.x) >> 6;
  int lane = threadIdx.x & 63;
  if (wid >= NN) return;
  const int g = lane >> 4, sub = lane & 15;
  int s0 = off[wid], s1 = off[wid + 1];

  float acc[4];
  #pragma unroll
  for (int k = 0; k < 4; ++k) acc[k] = 0.f;

  for (int e = s0; e < s1; e += 32) {
    unsigned v[8];
    #pragma unroll
    for (int k = 0; k < 8; ++k) {
      int ee = e + 4 * k + g;
      v[k] = 0u;
      if (ee < s1) v[k] = *(const unsigned*)(hl + (size_t)csr[ee] * 64 + sub * 4);
    }
    #pragma unroll
    for (int k = 0; k < 8; ++k) {
      floatx2 f;
      f = __builtin_amdgcn_cvt_pk_f32_fp8(v[k], false); acc[0] += f.x; acc[1] += f.y;
      f = __builtin_amdgcn_cvt_pk_f32_fp8(v[k], true);  acc[2] += f.x; acc[3] += f.y;
    }
  }

  #pragma unroll
  for (int k = 0; k < 4; ++k) {
    acc[k] += __shfl_xor(acc[k], 16);
    acc[k] += __shfl_xor(acc[k], 32);
  }

  float inv = 1.f / fmaxf((float)(s1 - s0), 1.f);
  int c = sub * 4 + g;                     // output column this lane writes
  float r = b2f(hr[(size_t)wid * 64 + c]);
  out[(size_t)wid * 64 + c] = fmaf(acc[g], inv, b2[c] + r);
}

// ---------------- launch ----------------

extern "C" void kernel_launch(void* const* d_in, const int* in_sizes, int n_in,
                              void* d_out, int out_size, void* d_ws, size_t ws_size,
                              hipStream_t stream) {
  const float* x   = (const float*)d_in[0];
  const int*   ei  = (const int*)d_in[1];
  const float* w1l = (const float*)d_in[2];
  const float* b1  = (const float*)d_in[3];
  const float* w1r = (const float*)d_in[4];
  const float* w2l = (const float*)d_in[5];
  const float* b2  = (const float*)d_in[6];
  const float* w2r = (const float*)d_in[7];
  float* out = (float*)d_out;

  const int* src = ei;
  const int* dst = ei + NE;

  int* bktCnt  = (int*)d_ws + W_BKT;
  int* bktBase = (int*)d_ws + W_BASE;
  int* bktCur  = (int*)d_ws + W_BCUR;
  int* off     = (int*)d_ws + W_OFF;
  int* part    = (int*)d_ws + W_PART;
  int* csr     = (int*)d_ws + W_CSR;
  unsigned short* b1p = (unsigned short*)((int*)d_ws + W_B1);
  unsigned short* b2p = (unsigned short*)((int*)d_ws + W_B2);
  unsigned char*  xq  = (unsigned char*)((int*)d_ws + W_XQ);   // fp8 [NN][128]
  unsigned short* xr  = (unsigned short*)((int*)d_ws + W_XR);  // bf16 [NN][128]
  unsigned short* h   = (unsigned short*)((int*)d_ws + W_H);   // bf16 [NN][128]
  unsigned char*  hl  = (unsigned char*)((int*)d_ws + W_HL);   // fp8 [NN][64]
  unsigned short* hr  = (unsigned short*)((int*)d_ws + W_HR);  // bf16 [NN][64]

  hipMemsetAsync(bktCnt, 0, 400 * 4, stream);

  prebucket_k<<<PB, 256, 0, stream>>>(dst, bktCnt);
  scanb_k<<<1, 512, 0, stream>>>(bktCnt, bktBase, bktCur);
  partition_k<<<PB, 256, 0, stream>>>(src, dst, bktCur, part);
  cfill_k<<<NBKT, 256, 0, stream>>>(part, bktBase, off, csr);
  prep_b_k<<<24, 256, 0, stream>>>(w1l, w1r, w2l, w2r, b1p, b2p);

  const int gb = (NN + 127) / 128;   // 782
  const int ab = (NN * 64 + 255) / 256;

  // GEMM1: xq = fp8(x @ W1l^T) [NN][128], xr = bf16(x @ W1r^T) [NN][128]
  gemm_k<256, true, 1><<<gb, 512, 0, stream>>>((const void*)x, NN, b1p, xr, xq);

  // agg1: h = bf16( relu(mean_fp8(xl) + b1 + xr) )
  agg1_k<<<ab, 256, 0, stream>>>(xq, xr, off, csr, b1, h);

  // GEMM2: hl = fp8(h @ W2l^T) [NN][64], hr = bf16(h @ W2r^T) [NN][64]
  gemm_k<128, false, 2><<<gb, 512, 0, stream>>>((const void*)h, NN, b2p, hl, hr);

  // agg2: out = mean_fp8(hl) + b2 + hr  (fp32)
  agg2_k<<<ab, 256, 0, stream>>>(hl, hr, off, csr, b2, out);
}

// Round 15
// 204.977 us; speedup vs baseline: 1.0187x; 1.0020x over previous
//
#include <hip/hip_runtime.h>

// ---------------------------------------------------------------------------
// GraphSAGE 2-layer (mean aggr), N=100000, E=1600000, 128 -> 128(relu) -> 64
// Project-then-aggregate; bf16 MFMA GEMMs with LDS-repacked coalesced
// epilogues; fp8 gathered features both layers (xq 12.8 MB, hl 6.4 MB);
// CSR via LDS-binned counting sort; aggregation = wave-per-node, 32 cache
// lines in flight per wave (at the ~2.8 TB/s random-line fabric ceiling).
// ---------------------------------------------------------------------------

namespace {
constexpr int NN   = 100000;
constexpr int NE   = 1600000;
constexpr int NBKT = 391;            // buckets of 256 nodes: dst >> 8
constexpr int PB   = 256;            // partition blocks
constexpr int CE   = NE / PB;        // 6250 edges per partition block

// workspace layout in 4-byte words (16B-aligned regions)
constexpr size_t W_BKT  = 0;         // int[392]  bucket counts
constexpr size_t W_BASE = 400;       // int[392]  bucket bases (excl scan)
constexpr size_t W_BCUR = 800;       // int[392]  bucket alloc cursors
constexpr size_t W_OFF  = 1200;      // int[100416] CSR row offsets
constexpr size_t W_PART = 101616;    // int[NE]   bucket-sorted packed edges
constexpr size_t W_CSR  = 1701616;   // int[NE]   CSR adjacency (src ids)
constexpr size_t W_B1   = 3301616;   // ushort[8*8*64*8] packed W1
constexpr size_t W_B2   = 3318000;   // ushort[4*8*64*8] packed W2
constexpr size_t W_XQ   = 3326192;   // fp8  [NN][128]  (xl, gathered, 12.8 MB)
constexpr size_t W_XR   = 6526192;   // bf16 [NN][128]  (xr, self path)
constexpr size_t W_H    = 12926192;  // bf16 [NN][128]
constexpr size_t W_HL   = 19326192;  // fp8  [NN][64]   (hl, gathered, 6.4 MB)
constexpr size_t W_HR   = 20926192;  // bf16 [NN][64]   (hr, self path)
// end = 24,126,192 words = 96.5 MB
}

using short8  = __attribute__((ext_vector_type(8)))  short;
using f32x16  = __attribute__((ext_vector_type(16))) float;
using floatx2 = __attribute__((ext_vector_type(2)))  float;

__device__ inline unsigned short f2b(float f) {   // fp32 -> bf16 RNE
  unsigned u = __builtin_bit_cast(unsigned, f);
  u = (u + 0x7fffu + ((u >> 16) & 1u)) >> 16;
  return (unsigned short)u;
}
__device__ inline float b2f_lo(unsigned u) { return __builtin_bit_cast(float, u << 16); }
__device__ inline float b2f_hi(unsigned u) { return __builtin_bit_cast(float, u & 0xffff0000u); }
__device__ inline float b2f(unsigned short s) { return __builtin_bit_cast(float, ((unsigned)s) << 16); }

// ---------------- CSR build: LDS-binned counting sort ----------------

__global__ __launch_bounds__(256) void prebucket_k(const int* __restrict__ dst,
                                                   int* __restrict__ bktCnt) {
  __shared__ int h[NBKT];
  int t = threadIdx.x;
  for (int j = t; j < NBKT; j += 256) h[j] = 0;
  __syncthreads();
  const int base = blockIdx.x * CE;
  for (int i = t; i < CE; i += 256) atomicAdd(&h[dst[base + i] >> 8], 1);
  __syncthreads();
  for (int j = t; j < NBKT; j += 256) if (h[j]) atomicAdd(&bktCnt[j], h[j]);
}

__global__ __launch_bounds__(512) void scanb_k(const int* __restrict__ bktCnt,
                                               int* __restrict__ bktBase,
                                               int* __restrict__ bktCur) {
  __shared__ int s[512];
  int t = threadIdx.x;
  int v = (t < NBKT) ? bktCnt[t] : 0;
  s[t] = v;
  __syncthreads();
  #pragma unroll
  for (int d = 1; d < 512; d <<= 1) {
    int u = (t >= d) ? s[t - d] : 0;
    __syncthreads();
    s[t] += u;
    __syncthreads();
  }
  int excl = s[t] - v;
  if (t <= NBKT) bktBase[t] = excl;       // bktBase[NBKT] = NE sentinel
  if (t < NBKT)  bktCur[t]  = excl;
}

__global__ __launch_bounds__(256) void partition_k(const int* __restrict__ src,
                                                   const int* __restrict__ dst,
                                                   int* __restrict__ bktCur,
                                                   int* __restrict__ part) {
  __shared__ int  hist[NBKT + 1];
  __shared__ int  lo[NBKT + 1];
  __shared__ int  cur[NBKT + 1];
  __shared__ int  gb[NBKT + 1];
  __shared__ int  sh[256];
  __shared__ int  stage[CE];
  __shared__ unsigned short sbkt[CE];
  int t = threadIdx.x;
  const int base = blockIdx.x * CE;

  for (int j = t; j < NBKT + 1; j += 256) hist[j] = 0;
  __syncthreads();
  for (int i = t; i < CE; i += 256) atomicAdd(&hist[dst[base + i] >> 8], 1);
  __syncthreads();

  int j0 = 2 * t, j1 = 2 * t + 1;
  int h0 = (j0 < NBKT) ? hist[j0] : 0;
  int h1 = (j1 < NBKT) ? hist[j1] : 0;
  int ps = h0 + h1;
  sh[t] = ps;
  __syncthreads();
  #pragma unroll
  for (int d = 1; d < 256; d <<= 1) {
    int u = (t >= d) ? sh[t - d] : 0;
    __syncthreads();
    sh[t] += u;
    __syncthreads();
  }
  int e0 = sh[t] - ps;
  if (j0 < NBKT + 1) { lo[j0] = e0; cur[j0] = e0; }
  if (j1 < NBKT + 1) { lo[j1] = e0 + h0; cur[j1] = e0 + h0; }
  __syncthreads();

  for (int i = t; i < CE; i += 256) {
    int d = dst[base + i], s = src[base + i];
    int b = d >> 8;
    int p = atomicAdd(&cur[b], 1);
    stage[p] = ((d & 255) << 23) | s;
    sbkt[p]  = (unsigned short)b;
  }
  __syncthreads();

  for (int j = t; j < NBKT; j += 256)
    gb[j] = hist[j] ? atomicAdd(&bktCur[j], hist[j]) : 0;
  __syncthreads();

  for (int i = t; i < CE; i += 256) {
    int b = sbkt[i];
    part[gb[b] + (i - lo[b])] = stage[i];
  }
}

__global__ __launch_bounds__(256) void cfill_k(const int* __restrict__ part,
                                               const int* __restrict__ bktBase,
                                               int* __restrict__ off,
                                               int* __restrict__ csr) {
  __shared__ int cnt[256];
  __shared__ int cur[256];
  __shared__ int sh[256];
  int t = threadIdx.x;
  const int b = blockIdx.x;
  const int beg = bktBase[b], end = bktBase[b + 1];

  cnt[t] = 0;
  __syncthreads();
  for (int i = beg + t; i < end; i += 256)
    atomicAdd(&cnt[((unsigned)part[i]) >> 23], 1);
  __syncthreads();

  int v = cnt[t];
  sh[t] = v;
  __syncthreads();
  #pragma unroll
  for (int d = 1; d < 256; d <<= 1) {
    int u = (t >= d) ? sh[t - d] : 0;
    __syncthreads();
    sh[t] += u;
    __syncthreads();
  }
  int excl = sh[t] - v;
  off[b * 256 + t] = beg + excl;
  cur[t] = excl;
  __syncthreads();

  for (int i = beg + t; i < end; i += 256) {
    int w = part[i];
    int j = ((unsigned)w) >> 23;
    int p = atomicAdd(&cur[j], 1);
    csr[beg + p] = w & 0x7FFFFF;
  }
}

// ---------------- pack weights into 32x32x16 MFMA B-fragment order ---------

__global__ void prep_b_k(const float* __restrict__ w1l, const float* __restrict__ w1r,
                         const float* __restrict__ w2l, const float* __restrict__ w2r,
                         unsigned short* __restrict__ b1p, unsigned short* __restrict__ b2p) {
  int e = blockIdx.x * blockDim.x + threadIdx.x;
  if (e >= 6144) return;
  bool g2 = e >= 4096;
  int le = g2 ? e - 4096 : e;
  int nf = le >> 9, kk = (le >> 6) & 7, l = le & 63;
  int n = nf * 32 + (l & 31), half = l >> 5;
  const float* Wlo = g2 ? w2l : w1l;
  const float* Whi = g2 ? w2r : w1r;
  int split = g2 ? 64 : 128;
  unsigned short o[8];
  #pragma unroll
  for (int j = 0; j < 8; ++j) {
    int k = kk * 16 + ((j >= 4) ? 8 : 0) + half * 4 + (j & 3);
    float v = (n < split) ? Wlo[(size_t)n * 128 + k] : Whi[(size_t)(n - split) * 128 + k];
    o[j] = f2b(v);
  }
  unsigned short* dstp = (g2 ? b2p : b1p) + (size_t)le * 8;
  *(short8*)dstp = __builtin_bit_cast(short8, *(const ulonglong2*)o);
}

// ---------------- MFMA GEMM: C[m,n] = sum_k A[m,k]*W[n,k], K=128 ----------
// LDS-repacked epilogue: acc -> LDS tile image (fp8 + bf16 regions), then
// coalesced uint4 stores.
// MODE 1: cols <128 -> fp8 to C2v ([M][128]); cols >=128 -> bf16 to Cv ([M][128]).
// MODE 2: cols <64  -> fp8 to Cv  ([M][64]);  cols >=64  -> bf16 to C2v ([M][64]).

template<int NCOLS, bool AFP32, int MODE>
__global__ __launch_bounds__(512, 2) void gemm_k(const void* __restrict__ Aptr, int M,
                                                 const unsigned short* __restrict__ Bpack,
                                                 void* __restrict__ Cv,
                                                 void* __restrict__ C2v) {
  constexpr int NF = NCOLS / 64;                 // n-frags per wave
  constexpr int QB = (MODE == 1) ? 128 : 64;     // fp8 cols per row
  constexpr int EPI = 128 * QB * 3;              // fp8 bytes + bf16 bytes
  constexpr int SZ  = EPI > 32768 ? EPI : 32768; // >= staging (32 KB)
  __shared__ __align__(16) char smem[SZ];
  unsigned short* As    = (unsigned short*)smem;
  unsigned char*  epi_q = (unsigned char*)smem;            // [128][QB] fp8
  unsigned short* epi_r = (unsigned short*)(smem + 128 * QB); // [128][QB] bf16

  const int t  = threadIdx.x;
  const int m0 = blockIdx.x * 128;

  // ---- stage A (bf16, XOR-swizzled 16B granules) ----
  #pragma unroll
  for (int i = 0; i < 4; ++i) {
    int G = t + 512 * i;
    int r = G >> 4, g = G & 15;
    int m = m0 + r;
    short8 v = {0, 0, 0, 0, 0, 0, 0, 0};
    if (AFP32) {
      if (m < M) {
        const float* p = (const float*)Aptr + (size_t)m * 128 + g * 8;
        float4 a = *(const float4*)p;
        float4 b = *(const float4*)(p + 4);
        v[0] = (short)f2b(a.x); v[1] = (short)f2b(a.y);
        v[2] = (short)f2b(a.z); v[3] = (short)f2b(a.w);
        v[4] = (short)f2b(b.x); v[5] = (short)f2b(b.y);
        v[6] = (short)f2b(b.z); v[7] = (short)f2b(b.w);
      }
    } else {
      if (m < M) v = *(const short8*)((const unsigned short*)Aptr + (size_t)m * 128 + g * 8);
    }
    *(short8*)(As + r * 128 + ((g ^ (r & 15)) << 3)) = v;
  }
  __syncthreads();

  const int wid = t >> 6, lane = t & 63;
  const int mw = wid >> 1, nw = wid & 1;
  const int m = mw * 32 + (lane & 31), half = lane >> 5;

  // ---- A fragments into registers (all K) ----
  short8 af[8];
  #pragma unroll
  for (int kk = 0; kk < 8; ++kk) {
    const unsigned* p0 = (const unsigned*)(As + m * 128 + (((2 * kk)     ^ (m & 15)) << 3) + half * 4);
    const unsigned* p1 = (const unsigned*)(As + m * 128 + (((2 * kk + 1) ^ (m & 15)) << 3) + half * 4);
    uint4 comb = make_uint4(p0[0], p0[1], p1[0], p1[1]);
    af[kk] = __builtin_bit_cast(short8, comb);
  }
  __syncthreads();   // all As reads done -> smem reusable as epilogue buffer

  // ---- MFMA + scatter into LDS epilogue image ----
  #pragma unroll
  for (int nf = 0; nf < NF; ++nf) {
    const int nfg = nw * NF + nf;
    f32x16 acc;
    #pragma unroll
    for (int i = 0; i < 16; ++i) acc[i] = 0.f;
    #pragma unroll
    for (int kk = 0; kk < 8; ++kk) {
      short8 bf = *(const short8*)(Bpack + ((size_t)((nfg * 8 + kk) * 64 + lane)) * 8);
      acc = __builtin_amdgcn_mfma_f32_32x32x16_bf16(af[kk], bf, acc, 0, 0, 0);
    }
    const int col = nfg * 32 + (lane & 31);
    #pragma unroll
    for (int q = 0; q < 4; ++q)
      #pragma unroll
      for (int rr = 0; rr < 4; ++rr) {
        int lr = mw * 32 + rr + 8 * q + 4 * half;     // local row 0..127
        float v = acc[q * 4 + rr];
        if (col < QB) {
          int p8 = __builtin_amdgcn_cvt_pk_fp8_f32(v, v, 0, false);
          epi_q[lr * QB + col] = (unsigned char)(p8 & 0xff);
        } else {
          epi_r[lr * QB + (col - QB)] = f2b(v);
        }
      }
  }
  __syncthreads();

  // ---- coalesced store-out ----
  if (MODE == 1) {
    // xq fp8: 128 x 128 B = 16 KB (1024 x 16 B)
    #pragma unroll
    for (int i = 0; i < 2; ++i) {
      int idx = t + 512 * i;
      int row = idx >> 3, c16 = idx & 7;
      int mo = m0 + row;
      if (mo < M)
        *(uint4*)((unsigned char*)C2v + (size_t)mo * 128 + c16 * 16) =
            *(const uint4*)(epi_q + row * 128 + c16 * 16);
    }
    // xr bf16: 128 x 256 B = 32 KB (2048 x 16 B)
    #pragma unroll
    for (int i = 0; i < 4; ++i) {
      int idx = t + 512 * i;
      int row = idx >> 4, c16 = idx & 15;
      int mo = m0 + row;
      if (mo < M)
        *(uint4*)((unsigned char*)Cv + (size_t)mo * 256 + c16 * 16) =
            *(const uint4*)((const unsigned char*)epi_r + row * 256 + c16 * 16);
    }
  } else {
    // hl fp8: 128 x 64 B = 8 KB (512 x 16 B)
    {
      int row = t >> 2, c16 = t & 3;
      int mo = m0 + row;
      if (mo < M)
        *(uint4*)((unsigned char*)Cv + (size_t)mo * 64 + c16 * 16) =
            *(const uint4*)(epi_q + row * 64 + c16 * 16);
    }
    // hr bf16: 128 x 128 B = 16 KB (1024 x 16 B)
    #pragma unroll
    for (int i = 0; i < 2; ++i) {
      int idx = t + 512 * i;
      int row = idx >> 3, c16 = idx & 7;
      int mo = m0 + row;
      if (mo < M)
        *(uint4*)((unsigned char*)C2v + (size_t)mo * 128 + c16 * 16) =
            *(const uint4*)((const unsigned char*)epi_r + row * 128 + c16 * 16);
    }
  }
}

// ---------------- layer-1 aggregate + bias + self + relu -------------------
// wave per node; 4 groups of 16 lanes; each group gathers 4 different edges'
// full fp8 rows (uint2 = 8 B/lane x 16 lanes = 128 B) -> 16 edges / 32 lines
// in flight per wave (measured at ~2.8 TB/s L2-miss fabric ceiling).

__global__ __launch_bounds__(256) void agg1_k(const unsigned char* __restrict__ xq,
                                              const unsigned short* __restrict__ xr,
                                              const int* __restrict__ off,
                                              const int* __restrict__ csr,
                                              const float* __restrict__ b1,
                                              unsigned short* __restrict__ h) {
  int wid  = (blockIdx.x * blockDim.x + threadIdx.x) >> 6;
  int lane = threadIdx.x & 63;
  if (wid >= NN) return;
  const int g = lane >> 4, sub = lane & 15;
  int s0 = off[wid], s1 = off[wid + 1];

  float acc[8];
  #pragma unroll
  for (int k = 0; k < 8; ++k) acc[k] = 0.f;

  for (int e = s0; e < s1; e += 16) {
    int e0 = e + g, e1 = e + 4 + g, e2 = e + 8 + g, e3 = e + 12 + g;
    uint2 v0 = make_uint2(0u, 0u), v1 = make_uint2(0u, 0u);
    uint2 v2 = make_uint2(0u, 0u), v3 = make_uint2(0u, 0u);
    if (e0 < s1) v0 = *(const uint2*)(xq + (size_t)csr[e0] * 128 + sub * 8);
    if (e1 < s1) v1 = *(const uint2*)(xq + (size_t)csr[e1] * 128 + sub * 8);
    if (e2 < s1) v2 = *(const uint2*)(xq + (size_t)csr[e2] * 128 + sub * 8);
    if (e3 < s1) v3 = *(const uint2*)(xq + (size_t)csr[e3] * 128 + sub * 8);
    floatx2 f;
    f = __builtin_amdgcn_cvt_pk_f32_fp8(v0.x, false); acc[0] += f.x; acc[1] += f.y;
    f = __builtin_amdgcn_cvt_pk_f32_fp8(v0.x, true);  acc[2] += f.x; acc[3] += f.y;
    f = __builtin_amdgcn_cvt_pk_f32_fp8(v0.y, false); acc[4] += f.x; acc[5] += f.y;
    f = __builtin_amdgcn_cvt_pk_f32_fp8(v0.y, true);  acc[6] += f.x; acc[7] += f.y;
    f = __builtin_amdgcn_cvt_pk_f32_fp8(v1.x, false); acc[0] += f.x; acc[1] += f.y;
    f = __builtin_amdgcn_cvt_pk_f32_fp8(v1.x, true);  acc[2] += f.x; acc[3] += f.y;
    f = __builtin_amdgcn_cvt_pk_f32_fp8(v1.y, false); acc[4] += f.x; acc[5] += f.y;
    f = __builtin_amdgcn_cvt_pk_f32_fp8(v1.y, true);  acc[6] += f.x; acc[7] += f.y;
    f = __builtin_amdgcn_cvt_pk_f32_fp8(v2.x, false); acc[0] += f.x; acc[1] += f.y;
    f = __builtin_amdgcn_cvt_pk_f32_fp8(v2.x, true);  acc[2] += f.x; acc[3] += f.y;
    f = __builtin_amdgcn_cvt_pk_f32_fp8(v2.y, false); acc[4] += f.x; acc[5] += f.y;
    f = __builtin_amdgcn_cvt_pk_f32_fp8(v2.y, true);  acc[6] += f.x; acc[7] += f.y;
    f = __builtin_amdgcn_cvt_pk_f32_fp8(v3.x, false); acc[0] += f.x; acc[1] += f.y;
    f = __builtin_amdgcn_cvt_pk_f32_fp8(v3.x, true);  acc[2] += f.x; acc[3] += f.y;
    f = __builtin_amdgcn_cvt_pk_f32_fp8(v3.y, false); acc[4] += f.x; acc[5] += f.y;
    f = __builtin_amdgcn_cvt_pk_f32_fp8(v3.y, true);  acc[6] += f.x; acc[7] += f.y;
  }

  #pragma unroll
  for (int k = 0; k < 8; ++k) {
    acc[k] += __shfl_xor(acc[k], 16);
    acc[k] += __shfl_xor(acc[k], 32);
  }

  float inv = 1.f / fmaxf((float)(s1 - s0), 1.f);
  int widx = sub * 4 + g;                  // uint word -> cols 2*widx, 2*widx+1
  unsigned su = ((const unsigned*)xr)[(size_t)wid * 64 + widx];
  float2 bb = *(const float2*)(b1 + 2 * widx);
  float h0 = fmaxf(fmaf(acc[2 * g],     inv, bb.x + b2f_lo(su)), 0.f);
  float h1 = fmaxf(fmaf(acc[2 * g + 1], inv, bb.y + b2f_hi(su)), 0.f);
  unsigned packed = (unsigned)f2b(h0) | ((unsigned)f2b(h1) << 16);
  ((unsigned*)h)[(size_t)wid * 64 + widx] = packed;
}

// ---------------- layer-2 aggregate + bias + self -> out (fp32) ------------
// grouped-gather; hl row = 64 fp8 = 64 B (one uint/lane); 8 gathers per
// group -> 32 edges / 32 lines in flight per wave.

__global__ __launch_bounds__(256) void agg2_k(const unsigned char* __restrict__ hl,
                                              const unsigned short* __restrict__ hr,
                                              const int* __restrict__ off,
                                              const int* __restrict__ csr,
                                              const float* __restrict__ b2,
                                              float* __restrict__ out) {
  int wid  = (blockIdx.x * blockDim.x + threadIdx.x) >> 6;
  int lane = threadIdx.x & 63;
  if (wid >= NN) return;
  const int g = lane >> 4, sub = lane & 15;
  int s0 = off[wid], s1 = off[wid + 1];

  float acc[4];
  #pragma unroll
  for (int k = 0; k < 4; ++k) acc[k] = 0.f;

  for (int e = s0; e < s1; e += 32) {
    unsigned v[8];
    #pragma unroll
    for (int k = 0; k < 8; ++k) {
      int ee = e + 4 * k + g;
      v[k] = 0u;
      if (ee < s1) v[k] = *(const unsigned*)(hl + (size_t)csr[ee] * 64 + sub * 4);
    }
    #pragma unroll
    for (int k = 0; k < 8; ++k) {
      floatx2 f;
      f = __builtin_amdgcn_cvt_pk_f32_fp8(v[k], false); acc[0] += f.x; acc[1] += f.y;
      f = __builtin_amdgcn_cvt_pk_f32_fp8(v[k], true);  acc[2] += f.x; acc[3] += f.y;
    }
  }

  #pragma unroll
  for (int k = 0; k < 4; ++k) {
    acc[k] += __shfl_xor(acc[k], 16);
    acc[k] += __shfl_xor(acc[k], 32);
  }

  float inv = 1.f / fmaxf((float)(s1 - s0), 1.f);
  int c = sub * 4 + g;                     // output column this lane writes
  float r = b2f(hr[(size_t)wid * 64 + c]);
  out[(size_t)wid * 64 + c] = fmaf(acc[g], inv, b2[c] + r);
}

// ---------------- launch ----------------

extern "C" void kernel_launch(void* const* d_in, const int* in_sizes, int n_in,
                              void* d_out, int out_size, void* d_ws, size_t ws_size,
                              hipStream_t stream) {
  const float* x   = (const float*)d_in[0];
  const int*   ei  = (const int*)d_in[1];
  const float* w1l = (const float*)d_in[2];
  const float* b1  = (const float*)d_in[3];
  const float* w1r = (const float*)d_in[4];
  const float* w2l = (const float*)d_in[5];
  const float* b2  = (const float*)d_in[6];
  const float* w2r = (const float*)d_in[7];
  float* out = (float*)d_out;

  const int* src = ei;
  const int* dst = ei + NE;

  int* bktCnt  = (int*)d_ws + W_BKT;
  int* bktBase = (int*)d_ws + W_BASE;
  int* bktCur  = (int*)d_ws + W_BCUR;
  int* off     = (int*)d_ws + W_OFF;
  int* part    = (int*)d_ws + W_PART;
  int* csr     = (int*)d_ws + W_CSR;
  unsigned short* b1p = (unsigned short*)((int*)d_ws + W_B1);
  unsigned short* b2p = (unsigned short*)((int*)d_ws + W_B2);
  unsigned char*  xq  = (unsigned char*)((int*)d_ws + W_XQ);   // fp8 [NN][128]
  unsigned short* xr  = (unsigned short*)((int*)d_ws + W_XR);  // bf16 [NN][128]
  unsigned short* h   = (unsigned short*)((int*)d_ws + W_H);   // bf16 [NN][128]
  unsigned char*  hl  = (unsigned char*)((int*)d_ws + W_HL);   // fp8 [NN][64]
  unsigned short* hr  = (unsigned short*)((int*)d_ws + W_HR);  // bf16 [NN][64]

  hipMemsetAsync(bktCnt, 0, 400 * 4, stream);

  prebucket_k<<<PB, 256, 0, stream>>>(dst, bktCnt);
  scanb_k<<<1, 512, 0, stream>>>(bktCnt, bktBase, bktCur);
  partition_k<<<PB, 256, 0, stream>>>(src, dst, bktCur, part);
  cfill_k<<<NBKT, 256, 0, stream>>>(part, bktBase, off, csr);
  prep_b_k<<<24, 256, 0, stream>>>(w1l, w1r, w2l, w2r, b1p, b2p);

  const int gb = (NN + 127) / 128;   // 782
  const int ab = (NN * 64 + 255) / 256;

  // GEMM1: xq = fp8(x @ W1l^T) [NN][128], xr = bf16(x @ W1r^T) [NN][128]
  gemm_k<256, true, 1><<<gb, 512, 0, stream>>>((const void*)x, NN, b1p, xr, xq);

  // agg1: h = bf16( relu(mean_fp8(xl) + b1 + xr) )
  agg1_k<<<ab, 256, 0, stream>>>(xq, xr, off, csr, b1, h);

  // GEMM2: hl = fp8(h @ W2l^T) [NN][64], hr = bf16(h @ W2r^T) [NN][64]
  gemm_k<128, false, 2><<<gb, 512, 0, stream>>>((const void*)h, NN, b2p, hl, hr);

  // agg2: out = mean_fp8(hl) + b2 + hr  (fp32)
  agg2_k<<<ab, 256, 0, stream>>>(hl, hr, off, csr, b2, out);
}